// Round 10
// baseline (74.234 us; speedup 1.0000x reference)
//
#include <hip/hip_runtime.h>
#include <math.h>
#include <stdint.h>

#define NN 8192
#define DD 1024
#define KT 2048   // 2*D
#define HH 100
#define HP 128    // padded hidden
#define LCAP 512
#define NB 32
#define BKC 64            // K per body
#define NSL 4             // K slices
#define KSL 512           // K per slice
#define NCHS (KSL / BKC)  // 8 bodies per slice

typedef short bf16x8 __attribute__((ext_vector_type(8)));
typedef short bf16x4 __attribute__((ext_vector_type(4)));
typedef float f32x4 __attribute__((ext_vector_type(4)));

__device__ __forceinline__ short f2bf(float f) {
    uint32_t u = __builtin_bit_cast(uint32_t, f);
    u += 0x7FFF + ((u >> 16) & 1);   // round-to-nearest-even
    return (short)(u >> 16);
}

// W1 fp32 [2048][100] -> w1p packed fragments (coalesced B loads):
// w1p[((c32*8 + tile)*64 + lane)*8 + j] = bf16(W1[c32*32 + (lane>>4)*8 + j][tile*16 + (lane&15)])
__global__ __launch_bounds__(256) void prep_w1p(const float* __restrict__ W1,
                                                short* __restrict__ w1p)
{
    __shared__ float ld[32][104];
    const int t  = threadIdx.x;
    const int k0 = blockIdx.x * 32;          // 64 blocks
    for (int i = t; i < 32 * HH; i += 256) {
        const int kk = i / HH, cc = i - kk * HH;
        ld[kk][cc] = W1[(size_t)(k0 + kk) * HH + cc];
    }
    __syncthreads();
    for (int idx = t; idx < 512; idx += 256) {
        const int tt = idx >> 6, l = idx & 63;
        const int lr = l & 15, lg = l >> 4;
        const int col = tt * 16 + lr;
        bf16x8 r;
#pragma unroll
        for (int j = 0; j < 8; ++j)
            r[j] = (col < HH) ? f2bf(ld[lg * 8 + j][col]) : (short)0;
        *(bf16x8*)(w1p + ((size_t)(blockIdx.x * 8 + tt) * 64 + l) * 8) = r;
    }
}

// Split-K phase A: 2048 blocks (rowblk 512 x slice 4), 256 thr / 4 waves.
// Block: 16 rows x 128 cols x K=512 -> fp32 partials. Same proven body as R9.
__global__ __launch_bounds__(256) void encoder_partial(
    const float* __restrict__ q, const float* __restrict__ x,
    const short* __restrict__ w1p, float* __restrict__ part)
{
    __shared__ short As[3][16][64];   // bf16, 8B-slot XOR swizzle
    const int t  = threadIdx.x;
    const int w  = t >> 6;            // wave 0..3
    const int l  = t & 63;
    const int lr = l & 15;
    const int lg = l >> 4;
    const int bid   = blockIdx.x;
    const int slice = bid & 3;
    const int r0    = (bid >> 2) * 16;

    // A staging: thread t loads float4 of row srow; slice base in q or x
    const int srow  = t >> 4;
    const int sslot = t & 15;
    const int wslot = sslot ^ srow;
    const float* base = ((slice < 2) ? q : x)
        + (size_t)(r0 + srow) * DD + (slice & 1) * KSL + sslot * 4;
    auto aptr = [&](int c) -> const float* { return base + c * BKC; };
    auto stage = [&](int buf, const float4& v) {
        bf16x4 s;
        s[0] = f2bf(v.x); s[1] = f2bf(v.y); s[2] = f2bf(v.z); s[3] = f2bf(v.w);
        *(bf16x4*)&As[buf][srow][wslot * 4] = s;
    };

    const int p0 = ((2 * lg)     ^ lr) * 4;
    const int p1 = ((2 * lg + 1) ^ lr) * 4;
    const int p2 = ((2 * lg + 8) ^ lr) * 4;
    const int p3 = ((2 * lg + 9) ^ lr) * 4;

    const short* pB = w1p + (size_t)slice * NCHS * 8192
                    + ((size_t)(2 * w) * 64 + l) * 8;
#define LOADB(c, x0, x1, x2, x3)                           \
    { const size_t e_ = (size_t)(c) * 8192;                \
      x0 = *(const bf16x8*)(pB + e_);                      \
      x1 = *(const bf16x8*)(pB + e_ + 4096);               \
      x2 = *(const bf16x8*)(pB + e_ + 512);                \
      x3 = *(const bf16x8*)(pB + e_ + 4096 + 512); }

    f32x4 acc0 = (f32x4)0.f, acc1 = (f32x4)0.f;
    bf16x8 bA0, bA1, bA2, bA3, bB0, bB1, bB2, bB3;

#define FRAGS_MFMA(rb, b0, b1_, b2_, b3_)                                   \
    { const short* ar = &As[rb][lr][0];                                     \
      bf16x4 g0 = *(const bf16x4*)(ar + p0);                                \
      bf16x4 g1 = *(const bf16x4*)(ar + p1);                                \
      bf16x4 g2 = *(const bf16x4*)(ar + p2);                                \
      bf16x4 g3 = *(const bf16x4*)(ar + p3);                                \
      bf16x8 aa0 = __builtin_shufflevector(g0, g1, 0,1,2,3,4,5,6,7);        \
      bf16x8 aa1 = __builtin_shufflevector(g2, g3, 0,1,2,3,4,5,6,7);        \
      acc0 = __builtin_amdgcn_mfma_f32_16x16x32_bf16(aa0, b0,  acc0, 0,0,0);\
      acc0 = __builtin_amdgcn_mfma_f32_16x16x32_bf16(aa1, b1_, acc0, 0,0,0);\
      acc1 = __builtin_amdgcn_mfma_f32_16x16x32_bf16(aa0, b2_, acc1, 0,0,0);\
      acc1 = __builtin_amdgcn_mfma_f32_16x16x32_bf16(aa1, b3_, acc1, 0,0,0); }

    float4 t0 = *(const float4*)aptr(0);
    float4 t1 = *(const float4*)aptr(1);
    float4 rE = *(const float4*)aptr(2);
    float4 rO = *(const float4*)aptr(3);
    LOADB(0, bA0, bA1, bA2, bA3);
    stage(0, t0);
    stage(1, t1);
    __syncthreads();

    int rb = 0;
#pragma unroll 1
    for (int c = 0; c < NCHS; c += 2) {
        { const int cn = c + 1 < NCHS ? c + 1 : NCHS - 1; LOADB(cn, bB0, bB1, bB2, bB3); }
        FRAGS_MFMA(rb, bA0, bA1, bA2, bA3);
        __syncthreads();
        { int wb = rb - 1; if (wb < 0) wb = 2;
          stage(wb, rE);
          rE = *(const float4*)aptr(c + 4 < NCHS ? c + 4 : NCHS - 1); }
        rb = (rb == 2) ? 0 : rb + 1;
        { const int cn = c + 2 < NCHS ? c + 2 : NCHS - 1; LOADB(cn, bA0, bA1, bA2, bA3); }
        FRAGS_MFMA(rb, bB0, bB1, bB2, bB3);
        __syncthreads();
        { int wb = rb - 1; if (wb < 0) wb = 2;
          stage(wb, rO);
          rO = *(const float4*)aptr(c + 5 < NCHS ? c + 5 : NCHS - 1); }
        rb = (rb == 2) ? 0 : rb + 1;
    }

    // store partials: part[slice][row][col]
    float* pp = part + ((size_t)slice * NN + r0) * HP;
#pragma unroll
    for (int r = 0; r < 4; ++r) {
        const int row = lg * 4 + r;
        pp[row * HP + w * 32 + lr]      = acc0[r];
        pp[row * HP + w * 32 + lr + 16] = acc1[r];
    }
#undef LOADB
#undef FRAGS_MFMA
}

// Phase B: 512 blocks x 256 thr; block = 16 rows. Sum 4 slices, bias+relu+W2,
// 16-lane shuffle reduce, compact into per-batch pos/neg lists.
__global__ __launch_bounds__(256) void reduce_score(
    const float* __restrict__ part,
    const float* __restrict__ b1, const float* __restrict__ W2,
    const float* __restrict__ b2,
    const int* __restrict__ bidx, const int* __restrict__ y,
    float* __restrict__ sp, float* __restrict__ sn,
    int* __restrict__ cnt1, int* __restrict__ cnt0)
{
    const int t   = threadIdx.x;
    const int row = t >> 4;           // 0..15
    const int cg  = t & 15;           // col group (8 cols)
    const int c0  = cg * 8;
    const int r0  = blockIdx.x * 16;
    const float* pr = part + ((size_t)(r0 + row)) * HP + c0;
    f32x4 s0 = (f32x4)0.f, s1 = (f32x4)0.f;
#pragma unroll
    for (int sl = 0; sl < NSL; ++sl) {
        const float* p = pr + (size_t)sl * NN * HP;
        s0 += *(const f32x4*)p;
        s1 += *(const f32x4*)(p + 4);
    }
    float acc = 0.f;
#pragma unroll
    for (int j = 0; j < 4; ++j) {
        const int ca = c0 + j, cb = c0 + 4 + j;
        const float ba = (ca < HH) ? b1[ca] : 0.f;
        const float wa = (ca < HH) ? W2[ca] : 0.f;
        const float bb = (cb < HH) ? b1[cb] : 0.f;
        const float wb = (cb < HH) ? W2[cb] : 0.f;
        acc = fmaf(fmaxf(s0[j] + ba, 0.f), wa, acc);
        acc = fmaf(fmaxf(s1[j] + bb, 0.f), wb, acc);
    }
    acc += __shfl_xor(acc, 1);
    acc += __shfl_xor(acc, 2);
    acc += __shfl_xor(acc, 4);
    acc += __shfl_xor(acc, 8);
    if (cg == 0) {
        const float sv = acc + b2[0];
        const int i = r0 + row;
        const int g = bidx[i];
        if (y[i]) {
            int idx = atomicAdd(&cnt1[g], 1);
            if (idx < LCAP) sp[g * LCAP + idx] = sv;
        } else {
            int idx = atomicAdd(&cnt0[g], 1);
            if (idx < LCAP) sn[g * LCAP + idx] = sv;
        }
    }
}

// grid = NB*8 blocks; block (g, sl) handles pos indices p ≡ sl (mod 8).
__global__ __launch_bounds__(256) void pairsum_kernel(
    const float* __restrict__ sp, const float* __restrict__ sn,
    const int* __restrict__ cnt1, const int* __restrict__ cnt0,
    float* __restrict__ partial)
{
    __shared__ float lsn[LCAP];
    __shared__ float lsp[64];
    __shared__ float wsum[4];
    const int g  = blockIdx.x >> 3;
    const int sl = blockIdx.x & 7;
    const int t  = threadIdx.x;
    const int n1 = min(cnt1[g], LCAP);
    const int n0 = min(cnt0[g], LCAP);
    for (int j = t; j < n0; j += 256) lsn[j] = sn[g * LCAP + j];
    const int np = (n1 > sl) ? ((n1 - sl + 7) >> 3) : 0;
    for (int j = t; j < np; j += 256) lsp[j] = sp[g * LCAP + sl + j * 8];
    __syncthreads();
    float acc = 0.f;
    const int total = np * n0;
    for (int u = t; u < total; u += 256) {
        const int ip = u / n0;
        const int j  = u - ip * n0;
        const float d  = lsn[j] - lsp[ip];          // s_neg - s_pos
        const float ad = fabsf(d);
        const float z  = __builtin_exp2f(-ad * 1.44269504f);
        acc += fmaxf(d, 0.f) + __builtin_log2f(1.f + z) * 0.69314718f;
    }
#pragma unroll
    for (int off = 32; off > 0; off >>= 1) acc += __shfl_xor(acc, off, 64);
    const int wid = t >> 6, lane = t & 63;
    if (lane == 0) wsum[wid] = acc;
    __syncthreads();
    if (t == 0) partial[blockIdx.x] = wsum[0] + wsum[1] + wsum[2] + wsum[3];
}

__global__ __launch_bounds__(256) void finalize_kernel(
    const float* __restrict__ partial,
    const int* __restrict__ cnt1, const int* __restrict__ cnt0,
    float* __restrict__ out)
{
    __shared__ float ws_[4], wc_[4];
    const int t = threadIdx.x;
    float sv = partial[t];   // 256 entries
    float cv = 0.f;
    if (t < NB) cv = (float)min(cnt1[t], LCAP) * (float)min(cnt0[t], LCAP);
#pragma unroll
    for (int off = 32; off > 0; off >>= 1) {
        sv += __shfl_xor(sv, off, 64);
        cv += __shfl_xor(cv, off, 64);
    }
    const int wid = t >> 6, lane = t & 63;
    if (lane == 0) { ws_[wid] = sv; wc_[wid] = cv; }
    __syncthreads();
    if (t == 0)
        out[0] = (ws_[0] + ws_[1] + ws_[2] + ws_[3]) /
                 (wc_[0] + wc_[1] + wc_[2] + wc_[3]);
}

extern "C" void kernel_launch(void* const* d_in, const int* in_sizes, int n_in,
                              void* d_out, int out_size, void* d_ws, size_t ws_size,
                              hipStream_t stream)
{
    const int*   b  = (const int*)d_in[0];
    const float* q  = (const float*)d_in[1];
    const float* x  = (const float*)d_in[2];
    const int*   y  = (const int*)d_in[3];
    const float* W1 = (const float*)d_in[4];
    const float* b1 = (const float*)d_in[5];
    const float* W2 = (const float*)d_in[6];
    const float* b2 = (const float*)d_in[7];
    float* out = (float*)d_out;

    char* base = (char*)d_ws;
    short* w1p     = (short*)base;                          // 512 KB packed B
    float* sp      = (float*)(base + 524288);               // 64 KB
    float* sn      = (float*)(base + 524288 + 65536);       // 64 KB
    int*   cnt1    = (int*)(base + 524288 + 131072);        // 128 B
    int*   cnt0    = cnt1 + NB;                             // 128 B
    float* partial = (float*)(base + 524288 + 131072 + 256);// 1 KB
    float* part    = (float*)(base + 1048576);              // 16 MB fp32 partials

    (void)hipMemsetAsync(cnt1, 0, 2 * NB * sizeof(int), stream);
    prep_w1p<<<KT / 32, 256, 0, stream>>>(W1, w1p);
    encoder_partial<<<(NN / 16) * NSL, 256, 0, stream>>>(q, x, w1p, part);
    reduce_score<<<NN / 16, 256, 0, stream>>>(part, b1, W2, b2,
                                              b, y, sp, sn, cnt1, cnt0);
    pairsum_kernel<<<NB * 8, 256, 0, stream>>>(sp, sn, cnt1, cnt0, partial);
    finalize_kernel<<<1, 256, 0, stream>>>(partial, cnt1, cnt0, out);
}

// Round 11
// 49.702 us; speedup vs baseline: 1.4936x; 1.4936x over previous
//
#include <hip/hip_runtime.h>
#include <math.h>
#include <stdint.h>

#define NN 8192
#define DD 1024
#define KT 2048   // 2*D
#define HH 100
#define HP 128    // padded hidden
#define LCAP 512
#define NB 32
#define BKC 64            // K per body
#define NBH 16            // bodies per K-half (1024/64)

typedef short bf16x8 __attribute__((ext_vector_type(8)));
typedef short bf16x4 __attribute__((ext_vector_type(4)));
typedef float f32x4 __attribute__((ext_vector_type(4)));

__device__ __forceinline__ short f2bf(float f) {
    uint32_t u = __builtin_bit_cast(uint32_t, f);
    u += 0x7FFF + ((u >> 16) & 1);   // round-to-nearest-even
    return (short)(u >> 16);
}

// W1 fp32 [2048][100] -> w1p packed fragments (coalesced B loads).
// Block 0 also zeroes the compaction counters (replaces hipMemsetAsync).
__global__ __launch_bounds__(256) void prep_w1p(const float* __restrict__ W1,
                                                short* __restrict__ w1p,
                                                int* __restrict__ cnt1,
                                                int* __restrict__ cnt0)
{
    __shared__ float ld[32][104];
    const int t  = threadIdx.x;
    if (blockIdx.x == 0 && t < 64) {
        if (t < 32) cnt1[t] = 0; else cnt0[t - 32] = 0;
    }
    const int k0 = blockIdx.x * 32;          // 64 blocks
    for (int i = t; i < 32 * HH; i += 256) {
        const int kk = i / HH, cc = i - kk * HH;
        ld[kk][cc] = W1[(size_t)(k0 + kk) * HH + cc];
    }
    __syncthreads();
    for (int idx = t; idx < 512; idx += 256) {
        const int tt = idx >> 6, l = idx & 63;
        const int lr = l & 15, lg = l >> 4;
        const int col = tt * 16 + lr;
        bf16x8 r;
#pragma unroll
        for (int j = 0; j < 8; ++j)
            r[j] = (col < HH) ? f2bf(ld[lg * 8 + j][col]) : (short)0;
        *(bf16x8*)(w1p + ((size_t)(blockIdx.x * 8 + tt) * 64 + l) * 8) = r;
    }
}

// 512 thr / 8 waves per block; 16 rows. Waves 0-3: K half 0 (q), cols (w&3)*32.
// Waves 4-7: K half 1 (x), same cols. Per-half A LDS triple-buffer pipeline
// (own 256-thread staging group), packed-B register double-buffer.
// Final: 8-way LDS fold + bias/relu/W2 + compaction.
__global__ __launch_bounds__(512) void encoder_mfma(
    const float* __restrict__ q, const float* __restrict__ x,
    const short* __restrict__ w1p,
    const float* __restrict__ b1, const float* __restrict__ W2,
    const float* __restrict__ b2,
    const int* __restrict__ bidx, const int* __restrict__ y,
    float* __restrict__ sp, float* __restrict__ sn,
    int* __restrict__ cnt1, int* __restrict__ cnt0)
{
    __shared__ short As[2][3][16][64];   // [half][buf], bf16, XOR-swizzled 8B slots
    __shared__ float fold[8][16];
    const int t    = threadIdx.x;
    const int w    = t >> 6;             // 0..7
    const int half = w >> 2;             // K half
    const int wc   = w & 3;              // col wave
    const int l    = t & 63;
    const int lr   = l & 15;
    const int lg   = l >> 4;
    const int r0   = blockIdx.x * 16;

    // A staging: group = half (t>>8 == w>>2); 256 threads stage 16x64 f32->bf16
    const int ts    = t & 255;
    const int srow  = ts >> 4;
    const int sslot = ts & 15;
    const int wslot = sslot ^ srow;
    const float* abase = (half ? x : q) + (size_t)(r0 + srow) * DD + sslot * 4;
    auto aptr  = [&](int c) -> const float* { return abase + c * BKC; };
    auto stage = [&](int buf, const float4& v) {
        bf16x4 s;
        s[0] = f2bf(v.x); s[1] = f2bf(v.y); s[2] = f2bf(v.z); s[3] = f2bf(v.w);
        *(bf16x4*)&As[half][buf][srow][wslot * 4] = s;
    };

    const int p0 = ((2 * lg)     ^ lr) * 4;
    const int p1 = ((2 * lg + 1) ^ lr) * 4;
    const int p2 = ((2 * lg + 8) ^ lr) * 4;
    const int p3 = ((2 * lg + 9) ^ lr) * 4;

    // packed B: body c of this half -> global body (half*16 + c)
    const short* pB = w1p + (size_t)half * NBH * 8192
                    + ((size_t)(2 * wc) * 64 + l) * 8;
#define LOADB(c, x0, x1, x2, x3)                           \
    { const size_t e_ = (size_t)(c) * 8192;                \
      x0 = *(const bf16x8*)(pB + e_);                      \
      x1 = *(const bf16x8*)(pB + e_ + 4096);               \
      x2 = *(const bf16x8*)(pB + e_ + 512);                \
      x3 = *(const bf16x8*)(pB + e_ + 4096 + 512); }

    f32x4 acc0 = (f32x4)0.f, acc1 = (f32x4)0.f;
    bf16x8 bA0, bA1, bA2, bA3, bB0, bB1, bB2, bB3;

#define FRAGS_MFMA(rb, b0, b1_, b2_, b3_)                                   \
    { const short* ar = &As[half][rb][lr][0];                               \
      bf16x4 g0 = *(const bf16x4*)(ar + p0);                                \
      bf16x4 g1 = *(const bf16x4*)(ar + p1);                                \
      bf16x4 g2 = *(const bf16x4*)(ar + p2);                                \
      bf16x4 g3 = *(const bf16x4*)(ar + p3);                                \
      bf16x8 aa0 = __builtin_shufflevector(g0, g1, 0,1,2,3,4,5,6,7);        \
      bf16x8 aa1 = __builtin_shufflevector(g2, g3, 0,1,2,3,4,5,6,7);        \
      acc0 = __builtin_amdgcn_mfma_f32_16x16x32_bf16(aa0, b0,  acc0, 0,0,0);\
      acc0 = __builtin_amdgcn_mfma_f32_16x16x32_bf16(aa1, b1_, acc0, 0,0,0);\
      acc1 = __builtin_amdgcn_mfma_f32_16x16x32_bf16(aa0, b2_, acc1, 0,0,0);\
      acc1 = __builtin_amdgcn_mfma_f32_16x16x32_bf16(aa1, b3_, acc1, 0,0,0); }

    // prologue: bodies 0,1 staged; A(2),A(3) in regs; B(0) in bA
    float4 t0 = *(const float4*)aptr(0);
    float4 t1 = *(const float4*)aptr(1);
    float4 rE = *(const float4*)aptr(2);
    float4 rO = *(const float4*)aptr(3);
    LOADB(0, bA0, bA1, bA2, bA3);
    stage(0, t0);
    stage(1, t1);
    __syncthreads();

    int rb = 0;
#pragma unroll 1
    for (int c = 0; c < NBH; c += 2) {
        { const int cn = c + 1 < NBH ? c + 1 : NBH - 1; LOADB(cn, bB0, bB1, bB2, bB3); }
        FRAGS_MFMA(rb, bA0, bA1, bA2, bA3);
        __syncthreads();
        { int wb = rb - 1; if (wb < 0) wb = 2;
          stage(wb, rE);
          rE = *(const float4*)aptr(c + 4 < NBH ? c + 4 : NBH - 1); }
        rb = (rb == 2) ? 0 : rb + 1;
        { const int cn = c + 2 < NBH ? c + 2 : NBH - 1; LOADB(cn, bA0, bA1, bA2, bA3); }
        FRAGS_MFMA(rb, bB0, bB1, bB2, bB3);
        __syncthreads();
        { int wb = rb - 1; if (wb < 0) wb = 2;
          stage(wb, rO);
          rO = *(const float4*)aptr(c + 5 < NBH ? c + 5 : NBH - 1); }
        rb = (rb == 2) ? 0 : rb + 1;
    }

    // epilogue: relu+W2 needs full K sum -> per-wave partial W2-dot is WRONG;
    // instead fold raw pre-activations: each wave writes its 32-col slice of
    // h[16][128] partial; cols overlap only across halves (wave w and w+4).
    // Use fold via LDS on the 32-col slices: first the two halves sum their
    // pre-activations per col, then relu+W2 reduce.
    __shared__ float hsum[16][HP + 4];
    if (half == 0) {
#pragma unroll
        for (int r = 0; r < 4; ++r) {
            hsum[lg * 4 + r][wc * 32 + lr]      = acc0[r];
            hsum[lg * 4 + r][wc * 32 + lr + 16] = acc1[r];
        }
    }
    __syncthreads();
    if (half == 1) {
#pragma unroll
        for (int r = 0; r < 4; ++r) {
            hsum[lg * 4 + r][wc * 32 + lr]      += acc0[r];
            hsum[lg * 4 + r][wc * 32 + lr + 16] += acc1[r];
        }
    }
    __syncthreads();
    // waves 0-3: relu+W2 over own 32 cols, 16-lane reduce, fold across waves
    if (half == 0) {
        const int c0 = wc * 32 + lr;
        const int c1 = c0 + 16;
        const float bb0 = (c0 < HH) ? b1[c0] : 0.f;
        const float ww0 = (c0 < HH) ? W2[c0] : 0.f;
        const float bb1 = (c1 < HH) ? b1[c1] : 0.f;
        const float ww1 = (c1 < HH) ? W2[c1] : 0.f;
#pragma unroll
        for (int r = 0; r < 4; ++r) {
            const int row = lg * 4 + r;
            float v = fmaf(fmaxf(hsum[row][c0] + bb0, 0.f), ww0,
                           fmaxf(hsum[row][c1] + bb1, 0.f) * ww1);
            v += __shfl_xor(v, 1);
            v += __shfl_xor(v, 2);
            v += __shfl_xor(v, 4);
            v += __shfl_xor(v, 8);
            if (lr == 0) fold[wc][row] = v;
        }
    }
    __syncthreads();
    if (t < 16) {
        const float sv = fold[0][t] + fold[1][t] + fold[2][t] + fold[3][t] + b2[0];
        const int i = r0 + t;
        const int g = bidx[i];
        if (y[i]) {
            int idx = atomicAdd(&cnt1[g], 1);
            if (idx < LCAP) sp[g * LCAP + idx] = sv;
        } else {
            int idx = atomicAdd(&cnt0[g], 1);
            if (idx < LCAP) sn[g * LCAP + idx] = sv;
        }
    }
#undef LOADB
#undef FRAGS_MFMA
}

// grid = NB*8 blocks; block (g, sl) handles pos indices p ≡ sl (mod 8).
__global__ __launch_bounds__(256) void pairsum_kernel(
    const float* __restrict__ sp, const float* __restrict__ sn,
    const int* __restrict__ cnt1, const int* __restrict__ cnt0,
    float* __restrict__ partial)
{
    __shared__ float lsn[LCAP];
    __shared__ float lsp[64];
    __shared__ float wsum[4];
    const int g  = blockIdx.x >> 3;
    const int sl = blockIdx.x & 7;
    const int t  = threadIdx.x;
    const int n1 = min(cnt1[g], LCAP);
    const int n0 = min(cnt0[g], LCAP);
    for (int j = t; j < n0; j += 256) lsn[j] = sn[g * LCAP + j];
    const int np = (n1 > sl) ? ((n1 - sl + 7) >> 3) : 0;
    for (int j = t; j < np; j += 256) lsp[j] = sp[g * LCAP + sl + j * 8];
    __syncthreads();
    float acc = 0.f;
    const int total = np * n0;
    for (int u = t; u < total; u += 256) {
        const int ip = u / n0;
        const int j  = u - ip * n0;
        const float d  = lsn[j] - lsp[ip];          // s_neg - s_pos
        const float ad = fabsf(d);
        const float z  = __builtin_exp2f(-ad * 1.44269504f);
        acc += fmaxf(d, 0.f) + __builtin_log2f(1.f + z) * 0.69314718f;
    }
#pragma unroll
    for (int off = 32; off > 0; off >>= 1) acc += __shfl_xor(acc, off, 64);
    const int wid = t >> 6, lane = t & 63;
    if (lane == 0) wsum[wid] = acc;
    __syncthreads();
    if (t == 0) partial[blockIdx.x] = wsum[0] + wsum[1] + wsum[2] + wsum[3];
}

__global__ __launch_bounds__(256) void finalize_kernel(
    const float* __restrict__ partial,
    const int* __restrict__ cnt1, const int* __restrict__ cnt0,
    float* __restrict__ out)
{
    __shared__ float ws_[4], wc_[4];
    const int t = threadIdx.x;
    float sv = partial[t];   // 256 entries
    float cv = 0.f;
    if (t < NB) cv = (float)min(cnt1[t], LCAP) * (float)min(cnt0[t], LCAP);
#pragma unroll
    for (int off = 32; off > 0; off >>= 1) {
        sv += __shfl_xor(sv, off, 64);
        cv += __shfl_xor(cv, off, 64);
    }
    const int wid = t >> 6, lane = t & 63;
    if (lane == 0) { ws_[wid] = sv; wc_[wid] = cv; }
    __syncthreads();
    if (t == 0)
        out[0] = (ws_[0] + ws_[1] + ws_[2] + ws_[3]) /
                 (wc_[0] + wc_[1] + wc_[2] + wc_[3]);
}

extern "C" void kernel_launch(void* const* d_in, const int* in_sizes, int n_in,
                              void* d_out, int out_size, void* d_ws, size_t ws_size,
                              hipStream_t stream)
{
    const int*   b  = (const int*)d_in[0];
    const float* q  = (const float*)d_in[1];
    const float* x  = (const float*)d_in[2];
    const int*   y  = (const int*)d_in[3];
    const float* W1 = (const float*)d_in[4];
    const float* b1 = (const float*)d_in[5];
    const float* W2 = (const float*)d_in[6];
    const float* b2 = (const float*)d_in[7];
    float* out = (float*)d_out;

    char* base = (char*)d_ws;
    short* w1p     = (short*)base;                          // 512 KB packed B
    float* sp      = (float*)(base + 524288);               // 64 KB
    float* sn      = (float*)(base + 524288 + 65536);       // 64 KB
    int*   cnt1    = (int*)(base + 524288 + 131072);        // 128 B
    int*   cnt0    = cnt1 + NB;                             // 128 B
    float* partial = (float*)(base + 524288 + 131072 + 256);// 1 KB

    prep_w1p<<<KT / 32, 256, 0, stream>>>(W1, w1p, cnt1, cnt0);
    encoder_mfma<<<NN / 16, 512, 0, stream>>>(q, x, w1p, b1, W2, b2,
                                              b, y, sp, sn, cnt1, cnt0);
    pairsum_kernel<<<NB * 8, 256, 0, stream>>>(sp, sn, cnt1, cnt0, partial);
    finalize_kernel<<<1, 256, 0, stream>>>(partial, cnt1, cnt0, out);
}